// Round 9
// baseline (31.185 us; speedup 1.0000x reference)
//
#include <hip/hip_runtime.h>

// LengthRegulator: out[b,c,t] = x[b,c,owner(b,t)] where owner(b,t) is the
// unique input token whose segment owns output frame t (path is a 0/1
// disjoint segment mask tiling [0,T_OUT), so bmm(x, path) == gather; exact).
//
// owner(b,t) is MONOTONE non-decreasing in t, so a block covering
// t in [t0, t0+64) only needs:
//   1) anchor scans: thread tid tests path[b,tid,t0] and path[b,tid,t0+64]
//      (one-hot columns -> exactly one thread hits each) -> o_lo, o_hi.
//   2) band scan: owner(t) in [o_lo,o_hi] (~17 rows avg) -> read only those
//      rows' 256B slices. Exactly one nonzero per t -> race-free conditional
//      LDS store, no init, no atomics.
//   3) expand: all 256 channels for this t-tile; gathers from x (8 MiB,
//      L1/L2-resident, band window ~2 lines per row) + coalesced float4
//      stores. Fused: no idx round-trip, no inter-kernel drain; 4 blocks/CU
//      so read phases overlap other blocks' write phases.

#define LR_B 32
#define LR_C 256
#define LR_TIN 256
#define LR_TOUT 2048
#define TT 64                    // t-tile per block

__global__ __launch_bounds__(256) void lr_fused5(const float* __restrict__ x,
                                                 const float* __restrict__ path,
                                                 float* __restrict__ out) {
    __shared__ int owner[TT];
    __shared__ int o_lo_s, o_hi_s;

    const int tid = threadIdx.x;
    const int t0 = blockIdx.x * TT;
    const int b  = blockIdx.y;
    const float* pb = path + (size_t)b * LR_TIN * LR_TOUT;

    // ---- anchors (one-hot columns) ----
    if (pb[(size_t)tid * LR_TOUT + t0] != 0.0f) o_lo_s = tid;
    if (t0 + TT < LR_TOUT) {
        if (pb[(size_t)tid * LR_TOUT + t0 + TT] != 0.0f) o_hi_s = tid;
    } else if (tid == 0) {
        o_hi_s = LR_TIN - 1;
    }
    __syncthreads();
    const int o_lo = o_lo_s;
    const int o_hi = o_hi_s;

    // ---- band scan: 16 rows x 16 float4-cols per pass ----
    const int col4 = tid & 15;           // float4 column within tile (16 x 4 = 64 t)
    const int row_off = tid >> 4;        // 0..15
    for (int r = o_lo + row_off; r <= o_hi; r += 16) {
        const float4 v = *reinterpret_cast<const float4*>(
            pb + (size_t)r * LR_TOUT + t0 + 4 * col4);
        if (v.x != 0.0f) owner[4 * col4 + 0] = r;
        if (v.y != 0.0f) owner[4 * col4 + 1] = r;
        if (v.z != 0.0f) owner[4 * col4 + 2] = r;
        if (v.w != 0.0f) owner[4 * col4 + 3] = r;
    }
    __syncthreads();

    // ---- expand: 256 channels, coalesced float4 stores ----
    const int4 iv = *reinterpret_cast<const int4*>(&owner[4 * col4]);
    const int cbase = tid >> 4;          // 0..15
    const float* xb = x + (size_t)b * LR_C * LR_TIN;
    float* ob = out + (size_t)b * LR_C * LR_TOUT + t0 + 4 * col4;
#pragma unroll
    for (int j = 0; j < LR_C / 16; ++j) {   // 16 iterations
        const int c = cbase + 16 * j;
        const float* xr = xb + (size_t)c * LR_TIN;
        float4 o;
        o.x = xr[iv.x];
        o.y = xr[iv.y];
        o.z = xr[iv.z];
        o.w = xr[iv.w];
        *reinterpret_cast<float4*>(ob + (size_t)c * LR_TOUT) = o;
    }
}

extern "C" void kernel_launch(void* const* d_in, const int* in_sizes, int n_in,
                              void* d_out, int out_size, void* d_ws, size_t ws_size,
                              hipStream_t stream) {
    const float* x    = (const float*)d_in[0];   // [B, C, T_IN] fp32
    const float* path = (const float*)d_in[1];   // [B, T_IN, T_OUT] fp32
    float* out = (float*)d_out;                  // [B, C, T_OUT] fp32
    lr_fused5<<<dim3(LR_TOUT / TT, LR_B), 256, 0, stream>>>(x, path, out);
}

// Round 10
// 25.811 us; speedup vs baseline: 1.2082x; 1.2082x over previous
//
#include <hip/hip_runtime.h>

// LengthRegulator: out[b,c,t] = x[b,c,owner(b,t)]; owner is the unique token
// whose segment covers frame t (path = 0/1 disjoint segment mask tiling
// [0,T_OUT) -> bmm(x,path) == gather; exact).
//
// K1 (banded idx build, unchanged from R8): owner(b,t) is monotone in t.
// Block (k,b): anchor scans at t0 and t0+128 give [o_lo,o_hi]; band scan of
// ~17 rows finds the one-hot per t; race-free conditional LDS store.
//
// K2 (FAT gather-expand): one block per (b, 8-channel chunk). 8 x-rows staged
// in LDS (8 KiB); idx loaded ONCE into registers (2 int4/thread) and reused
// across all 8 channels; per channel 8 LDS gathers + 2 contiguous float4
// stores (1 KiB per wave-store). 1024 blocks / 4096 waves instead of R8's
// 8192 blocks / 32768 waves -> amortizes wave-launch + idx traffic 8x.

#define LR_B 32
#define LR_C 256
#define LR_TIN 256
#define LR_TOUT 2048

#define SCAN_TT 128                   // t-interval per K1 block
#define CCHUNK 8                      // channels per K2 block

__global__ __launch_bounds__(256) void lr_idx5(const float* __restrict__ path,
                                               int* __restrict__ idx) {
    __shared__ int o_lo_s, o_hi_s;
    __shared__ int owner[SCAN_TT];

    const int tid = threadIdx.x;
    const int t0 = blockIdx.x * SCAN_TT;
    const int b = blockIdx.y;
    const float* pb = path + (size_t)b * LR_TIN * LR_TOUT;

    // ---- anchor scans (one-hot columns) ----
    if (pb[(size_t)tid * LR_TOUT + t0] != 0.0f) o_lo_s = tid;
    if (t0 + SCAN_TT < LR_TOUT) {
        if (pb[(size_t)tid * LR_TOUT + t0 + SCAN_TT] != 0.0f) o_hi_s = tid;
    } else if (tid == 0) {
        o_hi_s = LR_TIN - 1;
    }
    __syncthreads();
    const int o_lo = o_lo_s;
    const int o_hi = o_hi_s;

    // ---- band scan: 8 rows x 32 float4-cols per pass ----
    const int row_off = tid >> 5;     // 0..7
    const int col4 = tid & 31;        // float4 column within the 128-t tile
    for (int r = o_lo + row_off; r <= o_hi; r += 8) {
        const float4 v = *reinterpret_cast<const float4*>(
            pb + (size_t)r * LR_TOUT + t0 + 4 * col4);
        if (v.x != 0.0f) owner[4 * col4 + 0] = r;
        if (v.y != 0.0f) owner[4 * col4 + 1] = r;
        if (v.z != 0.0f) owner[4 * col4 + 2] = r;
        if (v.w != 0.0f) owner[4 * col4 + 3] = r;
    }
    __syncthreads();

    if (tid < SCAN_TT / 4) {
        const int4 o = *reinterpret_cast<const int4*>(&owner[4 * tid]);
        *reinterpret_cast<int4*>(idx + b * LR_TOUT + t0 + 4 * tid) = o;
    }
}

__global__ __launch_bounds__(256) void lr_gather5(const float* __restrict__ x,
                                                  const int* __restrict__ idx,
                                                  float* __restrict__ out) {
    __shared__ float xs[CCHUNK][LR_TIN];   // 8 KiB

    const int c0 = blockIdx.x * CCHUNK;
    const int b = blockIdx.y;
    const int tid = threadIdx.x;

    // stage 8 x-rows (coalesced: 8 rows x 256 floats = 8 KiB)
    {
        const float* xb = x + ((size_t)b * LR_C + c0) * LR_TIN;
#pragma unroll
        for (int ch = 0; ch < CCHUNK; ++ch) {
            xs[ch][tid] = xb[(size_t)ch * LR_TIN + tid];
        }
    }

    // idx once, reused for all channels
    const int* ib = idx + b * LR_TOUT;
    const int t0 = 4 * tid;
    const int4 iv0 = *reinterpret_cast<const int4*>(ib + t0);
    const int4 iv1 = *reinterpret_cast<const int4*>(ib + t0 + LR_TOUT / 2);
    __syncthreads();

    float* ob = out + ((size_t)b * LR_C + c0) * LR_TOUT;
#pragma unroll
    for (int ch = 0; ch < CCHUNK; ++ch) {
        float4 o0, o1;
        o0.x = xs[ch][iv0.x]; o0.y = xs[ch][iv0.y];
        o0.z = xs[ch][iv0.z]; o0.w = xs[ch][iv0.w];
        o1.x = xs[ch][iv1.x]; o1.y = xs[ch][iv1.y];
        o1.z = xs[ch][iv1.z]; o1.w = xs[ch][iv1.w];
        float* oc = ob + (size_t)ch * LR_TOUT;
        *reinterpret_cast<float4*>(oc + t0) = o0;
        *reinterpret_cast<float4*>(oc + t0 + LR_TOUT / 2) = o1;
    }
}

// Fallback if workspace is too small: fused banded kernel (correct, slower).
__global__ __launch_bounds__(256) void lr_fused5(const float* __restrict__ x,
                                                 const float* __restrict__ path,
                                                 float* __restrict__ out) {
    __shared__ int owner[64];
    __shared__ int o_lo_s, o_hi_s;
    const int tid = threadIdx.x;
    const int t0 = blockIdx.x * 64;
    const int b  = blockIdx.y;
    const float* pb = path + (size_t)b * LR_TIN * LR_TOUT;

    if (pb[(size_t)tid * LR_TOUT + t0] != 0.0f) o_lo_s = tid;
    if (t0 + 64 < LR_TOUT) {
        if (pb[(size_t)tid * LR_TOUT + t0 + 64] != 0.0f) o_hi_s = tid;
    } else if (tid == 0) {
        o_hi_s = LR_TIN - 1;
    }
    __syncthreads();
    const int o_lo = o_lo_s;
    const int o_hi = o_hi_s;

    const int col4 = tid & 15;
    const int row_off = tid >> 4;
    for (int r = o_lo + row_off; r <= o_hi; r += 16) {
        const float4 v = *reinterpret_cast<const float4*>(
            pb + (size_t)r * LR_TOUT + t0 + 4 * col4);
        if (v.x != 0.0f) owner[4 * col4 + 0] = r;
        if (v.y != 0.0f) owner[4 * col4 + 1] = r;
        if (v.z != 0.0f) owner[4 * col4 + 2] = r;
        if (v.w != 0.0f) owner[4 * col4 + 3] = r;
    }
    __syncthreads();

    const int4 iv = *reinterpret_cast<const int4*>(&owner[4 * col4]);
    const int cbase = tid >> 4;
    const float* xb = x + (size_t)b * LR_C * LR_TIN;
    float* ob = out + (size_t)b * LR_C * LR_TOUT + t0 + 4 * col4;
#pragma unroll
    for (int j = 0; j < LR_C / 16; ++j) {
        const int c = cbase + 16 * j;
        const float* xr = xb + (size_t)c * LR_TIN;
        float4 o;
        o.x = xr[iv.x]; o.y = xr[iv.y]; o.z = xr[iv.z]; o.w = xr[iv.w];
        *reinterpret_cast<float4*>(ob + (size_t)c * LR_TOUT) = o;
    }
}

extern "C" void kernel_launch(void* const* d_in, const int* in_sizes, int n_in,
                              void* d_out, int out_size, void* d_ws, size_t ws_size,
                              hipStream_t stream) {
    const float* x    = (const float*)d_in[0];   // [B, C, T_IN] fp32
    const float* path = (const float*)d_in[1];   // [B, T_IN, T_OUT] fp32
    float* out = (float*)d_out;                  // [B, C, T_OUT] fp32

    const size_t idx_bytes = (size_t)LR_B * LR_TOUT * sizeof(int);
    if (ws_size >= idx_bytes) {
        int* idx = (int*)d_ws;
        lr_idx5<<<dim3(LR_TOUT / SCAN_TT, LR_B), 256, 0, stream>>>(path, idx);
        lr_gather5<<<dim3(LR_C / CCHUNK, LR_B), 256, 0, stream>>>(x, idx, out);
    } else {
        lr_fused5<<<dim3(LR_TOUT / 64, LR_B), 256, 0, stream>>>(x, path, out);
    }
}